// Round 9
// baseline (4657.625 us; speedup 1.0000x reference)
//
#include <hip/hip_runtime.h>
#include <math.h>

// EMMA_38792144617759 v17 — v16 (passed, 3.46ms) with ONE change class: DEQ
// atomics ELIMINATED via column-split phase B. v16's counters showed
// WRITE_SIZE 545MB = exactly the 524K fp32 atomics/iter of the K-split dotB;
// those atomics (32-way same-address contention + vmcnt(0) drain) were ~6-7us
// of every 10.9us phase. Now: each WG owns 16 COMPLETE z_next columns
// (full K=1024; W2 col-slice 64KB LDS-resident); T crosses WGs via the proven
// sc1 store->lbar->load round-trip (phase A stores 128 T vals; phase B stages
// 4096 T into LDS); z_next = z + 0.5*(t@W2+b2) computed whole, written by
// PLAIN sc1 store. No atomics, no delta-fold, no zeroing (full overwrite).
// 4-way K-quarter partials reduced through a 256-float LDS buffer (wave=q ->
// conflict-free weight reads, c-stride 1028 pad = 2-way/free). 2 lbars/iter
// (289->545 phases) but each v10-class light (~3us) vs atomic-laden 10.9us.
// Phase A / window tasks / L1 / preamble / epilogue / k1,k3,k4: v16 verbatim.

#define NGRP 8
#define WPG  32

// ---- workspace float offsets (wsF = d_ws + 16KB; first 16KB is int region) ----
#define OF_SCALE  0
#define OF_DFAC   32
#define OF_RNV    64
#define OF_TOPW   1088
#define OF_SCORES 1600      // 32*4096
#define OF_Z      132672    // 2*32*512 (double-buffered z)
#define OF_T      165440    // 32*1024 (global T, reinstated for col-split B)
#define OF_CP     198208    // 32*1024 (global CP)
#define OF_G      230976    // 32*512
#define OF_TAU    247360    // 32*512
#define OF_H      263744    // 32*512
#define OF_ZS     280128    // 32*512
#define OF_HS     296512    // 32*512
#define OF_M      312896    // 4096*256
// transposed weight copies (filled by emma_tr before k2):
#define OF_W1ZT   1361472   // [1024 c][512 k]  = u_W1[k][c], k<512
#define OF_W1XT   1885760   // [1024 c][256 k]  = u_W1[512+k][c]
#define OF_W2T    2147904   // [512 c][1024 k]  = u_W2[k][c]
#define OF_LWIT   2672192   // [512 c][512 k]   = l_Wi[k][c]
#define OF_LWHT   2934336   // [512 c][512 k]   = l_Wh[k][c]
#define OF_LWTIT  3196480   // [512 c][512 k]   = l_Wti[k][c]
#define OF_LWTHT  3458624   // [512 c][512 k]   = l_Wth[k][c]
// wsI: [0..2048) barrier flags region (g*32+w used), [2048..2560) top_i

__device__ __forceinline__ float softplusf_(float x){ return x > 20.f ? x : log1pf(expf(x)); }

__device__ __forceinline__ float cldf(const float* p){
  return __hip_atomic_load(p, __ATOMIC_RELAXED, __HIP_MEMORY_SCOPE_AGENT);
}
__device__ __forceinline__ void cstf(float* p, float v){
  __hip_atomic_store(p, v, __ATOMIC_RELAXED, __HIP_MEMORY_SCOPE_AGENT);
}

// Light fence-free barrier (PROVEN v10-v16): all cross-WG data moves via sc1
// (LLC) ops; vmcnt(0) drains this wave's sc1 stores/atomics before the flag.
__device__ __forceinline__ void lbar(int* flags, int w, int& epoch){
  asm volatile("s_waitcnt vmcnt(0)" ::: "memory");
  __syncthreads();
  epoch++;
  if (threadIdx.x == 0)
    __hip_atomic_store(&flags[w], epoch, __ATOMIC_RELAXED, __HIP_MEMORY_SCOPE_AGENT);
  if (threadIdx.x < 32){
    while (__hip_atomic_load(&flags[threadIdx.x], __ATOMIC_RELAXED,
                             __HIP_MEMORY_SCOPE_AGENT) < epoch)
      __builtin_amdgcn_s_sleep(1);
  }
  asm volatile("" ::: "memory");
  __syncthreads();
}

// ---------------- kernel 0: generic row-major -> col-major transpose ----------------
__global__ void __launch_bounds__(256) emma_tr(const float* src, float* dst,
                                               int shift, int total)
{
  const int R = total >> shift;
  const int cmask = (1 << shift) - 1;
  for (int idx = blockIdx.x*256 + threadIdx.x; idx < total; idx += gridDim.x*256){
    int r = idx >> shift, c = idx & cmask;
    dst[(size_t)c * R + r] = src[idx];
  }
}

// ---------------- kernel 1a: scores, M zero, value-row norms, misc (v16 verbatim) ----------------
__global__ void __launch_bounds__(256) emma_k1a(
    const int* key_ids, const int* write_pos,
    const float* key_W, const float* value_W, const float* slot_keys,
    const float* lsr, int* wsI, float* wsF)
{
  const int wg = blockIdx.x, tid = threadIdx.x;
  if (wg < 256) {
    const int b = wg >> 3, chunk = wg & 7;
    __shared__ __align__(16) float s_kv[256];
    __shared__ float red[256];
    float v = key_W[key_ids[b]*256 + tid];
    red[tid] = v*v; __syncthreads();
    for (int st=128; st; st>>=1){ if (tid<st) red[tid]+=red[tid+st]; __syncthreads(); }
    float inv = 1.f/fmaxf(sqrtf(red[0]), 1e-12f);
    s_kv[tid] = v*inv;
    __syncthreads();
    const int lane = tid & 63, wv = tid >> 6;
    float4 kv4 = *(const float4*)(s_kv + lane*4);
    for (int slot = chunk*512 + wv; slot < chunk*512 + 512; slot += 4){
      float4 sk = *(const float4*)(slot_keys + (size_t)slot*256 + lane*4);
      float p = kv4.x*sk.x + kv4.y*sk.y + kv4.z*sk.z + kv4.w*sk.w;
      #pragma unroll
      for (int m=32;m;m>>=1) p += __shfl_xor(p, m, 64);
      if (lane==0) wsF[OF_SCORES + b*4096 + slot] = p;
    }
  } else if (wg < 320) {
    const int j = wg - 256;
    for (int i=tid;i<16384;i+=256) wsF[OF_M + j*16384 + i] = 0.f;
  } else if (wg < 324) {
    const int row = (wg-320)*256 + tid;
    float ss=0.f; const float* r = value_W + (size_t)row*256;
    for (int k=0;k<256;k++){ float x=r[k]; ss += x*x; }
    wsF[OF_RNV + row] = 1.f/fmaxf(sqrtf(ss), 1e-12f);
  } else {
    for (int i=tid;i<2048;i+=256) wsI[i]=0;
    __shared__ int pres[32];
    if (tid<32){ int p=0; for (int bb=0;bb<32;bb++) if (write_pos[bb]==tid) p=1; pres[tid]=p; }
    __syncthreads();
    if (tid<32){
      int wp = write_pos[tid]; float f=1.f;
      for (int s=wp+1;s<32;s++) if (pres[s]) f *= 0.997f;
      wsF[OF_DFAC + tid] = f;
    }
    if (tid==0) wsF[OF_SCALE] = softplusf_(lsr[0]) + 1e-3f;
  }
}

// ---------------- kernel 1b: exact top-16 + softmax (v16 verbatim) ----------------
__global__ void __launch_bounds__(256) emma_k1b(int* wsI, float* wsF)
{
  const int b = blockIdx.x, tid = threadIdx.x;
  __shared__ float s_sc[4096];
  __shared__ float s_rv[256]; __shared__ int s_ri[256];
  __shared__ float s_tv[16];
  for (int n=tid;n<4096;n+=256) s_sc[n] = wsF[OF_SCORES + b*4096 + n];
  __syncthreads();
  for (int j=0;j<16;j++){
    float bv = -3.0e38f; int bi = 0x7fffffff;
    for (int n=tid;n<4096;n+=256){
      float v = s_sc[n];
      if (v > bv || (v == bv && n < bi)) { bv=v; bi=n; }
    }
    s_rv[tid]=bv; s_ri[tid]=bi; __syncthreads();
    for (int st=128; st; st>>=1){
      if (tid<st){
        float v2=s_rv[tid+st]; int i2=s_ri[tid+st];
        if (v2 > s_rv[tid] || (v2==s_rv[tid] && i2 < s_ri[tid])) { s_rv[tid]=v2; s_ri[tid]=i2; }
      }
      __syncthreads();
    }
    if (tid==0){
      s_tv[j] = s_rv[0];
      wsI[2048 + b*16 + j] = s_ri[0];
      s_sc[s_ri[0]] = -3.0e38f;
    }
    __syncthreads();
  }
  if (tid==0){
    float mx = s_tv[0], sum=0.f, w[16];
    for (int j=0;j<16;j++){ w[j]=expf(s_tv[j]-mx); sum+=w[j]; }
    for (int j=0;j<16;j++) wsF[OF_TOPW + b*16 + j] = w[j]/sum;
  }
}

// ---------------- kernel 2: persistent trajectory (col-split B, zero DEQ atomics) ----------------
__global__ void __launch_bounds__(256, 1) emma_k2(
    const int* tokens, const int* write_pos,
    const float* embed_W, const float* u_b1, const float* u_b2,
    const float* l_b, const float* l_bt, const float* h0,
    int* wsI, float* wsF)
{
  const int g = blockIdx.x & 7;
  const int w = blockIdx.x >> 3;
  const int tid = threadIdx.x;
  int* flags = wsI + g*32;
  int epoch = 0;

  float* Z  = wsF + OF_Z;
  float* T  = wsF + OF_T;
  float* CP = wsF + OF_CP;
  float* G  = wsF + OF_G;
  float* TA = wsF + OF_TAU;
  float* H  = wsF + OF_H;
  float* ZS = wsF + OF_ZS;
  float* HS = wsF + OF_HS;

  __shared__ __align__(16) float4 ldsA[32*129];   // W1ZT cols [w*32,+32), 129-f4 pad  (66048 B)
  __shared__ __align__(16) float  ldsB2[16*1028]; // W2 col-slice [c][k], c2=w*16+c    (65792 B)
  __shared__ __align__(16) float  zstage[4*520];  // group z [4][520-pad]              (8320 B)
  __shared__ __align__(16) float  tstage[4*1032]; // group T [4][1032-pad]             (16512 B)
  __shared__ float redB[256];                     // phase-B K-quarter partials        (1024 B)

  // ---- stage per-WG weight slices into LDS (once) ----
  {
    const float* gA = wsF + OF_W1ZT + (size_t)(w*32)*512;
    const float* gB = wsF + OF_W2T  + (size_t)(w*16)*1024;
    for (int idx4 = tid; idx4 < 4096; idx4 += 256){
      { int ci = idx4 >> 7, j = idx4 & 127;
        ldsA[ci*129 + j] = *(const float4*)(gA + (size_t)ci*512 + 4*j); }
      { int c = idx4 >> 8, j = idx4 & 255;
        *(float4*)(ldsB2 + c*1028 + 4*j) = *(const float4*)(gB + (size_t)c*1024 + 4*j); }
    }
  }

  // per-thread loop-invariant constants
  const int rA  = tid >> 5;            // valid for tid<128 phases
  const int bA  = g*4 + (rA & 3);
  const int ciA = tid & 31;
  const int cA  = w*32 + ciA;          // dotA output col (global k index)
  const int qB  = tid >> 6;            // phase-B K-quarter (wave index)
  const int rB  = (tid >> 4) & 3;      // phase-B row
  const int cB  = tid & 15;            // phase-B local col
  const int kh  = w >> 4;              // L1 k-half
  const float b2v = u_b2[w*16 + cB];   // bias for this thread's owned c2 (tid<64 use)

  // ---- preamble: z buf0 = 0, h=h0 | c_pre for step 0 ----
  if (w < 16) {
    int idx = w*256 + tid;
    if (idx < 2048) cstf(&Z[g*2048 + idx], 0.f);
    else { int i2=idx-2048; int r=i2>>9, c=i2&511; cstf(&H[(g*4+r)*512 + c], h0[c]); }
  } else {
    int r = tid>>6, b = g*4+r;
    int c = (w-16)*64 + (tid&63);
    int tok = tokens[b*64 + 0];
    const float* xr = embed_W + (size_t)tok*256;
    const float* wc = wsF + OF_W1XT + (size_t)c*256;
    float a0=0,a1=0,a2=0,a3=0;
    #pragma unroll 4
    for (int k=0;k<256;k+=4){
      float4 xv = *(const float4*)(xr + k);
      float4 wv = *(const float4*)(wc + k);
      a0 += xv.x*wv.x; a1 += xv.y*wv.y; a2 += xv.z*wv.z; a3 += xv.w*wv.w;
    }
    cstf(&CP[b*1024 + c], u_b1[c] + ((a0+a1)+(a2+a3)));
  }
  lbar(flags, w, epoch);

  for (int s=0;s<32;s++){
    // CP fixed across the 8 DEQ iters — hoist (sc1; lbar precedes).
    float cpv = (tid < 128) ? cldf(&CP[bA*1024 + cA]) : 0.f;
    for (int i=0;i<8;i++){
      float* zc = Z + (i&1)*16384;      // holds z_i (complete)
      float* zn = Z + ((i&1)^1)*16384;  // fully overwritten with z_{i+1} in phase B
      // ---- phase A: stage z_i; dotA -> global T; window tasks on tid>=128
      #pragma unroll
      for (int k=0;k<8;k++){
        int idx = k*256 + tid;
        zstage[(idx>>9)*520 + (idx&511)] = cldf(&zc[g*2048 + idx]);
      }
      __syncthreads();
      if (tid < 128) {
        const float4* wc4 = ldsA + ciA*129;
        const float*  zr  = zstage + rA*520;
        float a0=0,a1=0,a2=0,a3=0;
        #pragma unroll 8
        for (int j=0;j<128;j++){
          float4 wv = wc4[j];
          float4 zv = *(const float4*)(zr + 4*j);
          a0 += zv.x*wv.x; a1 += zv.y*wv.y; a2 += zv.z*wv.z; a3 += zv.w*wv.w;
        }
        cstf(&T[bA*1024 + cA], tanhf(cpv + (a0+a1)+(a2+a3)));
      } else {
        if (i == 0 && w < 16 && s >= 1) {
          // h-update for step s-1 (G/TA complete after L1(s-1) lbar) + snapshots
          int idx = w*128 + (tid-128);
          int r = idx>>9, c2 = idx&511, b = g*4+r;
          float gv = tanhf(cldf(&G[b*512+c2]));
          float tv = softplusf_(cldf(&TA[b*512+c2])) + 1.0f;
          float hv = cldf(&H[b*512+c2]);
          float hn = hv + (gv - hv)/tv;
          cstf(&H[b*512+c2], hn);
          if (write_pos[b] == s-1) {
            cstf(&ZS[b*512+c2], zstage[r*520 + c2]);   // z final of step s-1
            cstf(&HS[b*512+c2], hn);
          }
        } else if (i <= 1 && w >= 16 && s+1 < 32) {
          // CP for step s+1 (static inputs), half per iter
          int e = i*2048 + (w-16)*128 + (tid-128);
          int r = e>>10, c = e&1023, b = g*4+r;
          int tok = tokens[b*64 + s+1];
          const float* xr = embed_W + (size_t)tok*256;
          const float* wc = wsF + OF_W1XT + (size_t)c*256;
          float a0=0,a1=0,a2=0,a3=0;
          #pragma unroll 4
          for (int k=0;k<256;k+=4){
            float4 xv = *(const float4*)(xr + k);
            float4 wv = *(const float4*)(wc + k);
            a0 += xv.x*wv.x; a1 += xv.y*wv.y; a2 += xv.z*wv.z; a3 += xv.w*wv.w;
          }
          cstf(&CP[b*1024 + c], u_b1[c] + ((a0+a1)+(a2+a3)));
        } else if (i == 7) {
          // init liquid pre-act buffers with biases for L1(s)
          int idx = w*128 + (tid-128);
          if (idx < 2048){ int r=idx>>9, c=idx&511; cstf(&G[(g*4+r)*512+c], l_b[c]); }
          else { int i2=idx-2048; int r=i2>>9, c=i2&511; cstf(&TA[(g*4+r)*512+c], l_bt[c]); }
        }
      }
      lbar(flags, w, epoch);
      // ---- phase B: stage T; full-K col-split dot; plain-store z_{i+1}
      #pragma unroll
      for (int k=0;k<16;k++){
        int idx = k*256 + tid;
        tstage[(idx>>10)*1032 + (idx&1023)] = cldf(&T[g*4096 + idx]);
      }
      __syncthreads();
      {
        const float* trow = tstage + rB*1032 + qB*256;
        const float* wrow = ldsB2 + cB*1028 + qB*256;
        float a0=0,a1=0,a2=0,a3=0;
        #pragma unroll 8
        for (int j=0;j<64;j++){
          float4 tv = *(const float4*)(trow + 4*j);
          float4 wv = *(const float4*)(wrow + 4*j);
          a0 += tv.x*wv.x; a1 += tv.y*wv.y; a2 += tv.z*wv.z; a3 += tv.w*wv.w;
        }
        redB[tid] = (a0+a1)+(a2+a3);
      }
      __syncthreads();
      if (tid < 64){
        float sum = redB[tid] + redB[tid+64] + redB[tid+128] + redB[tid+192];
        int c2 = w*16 + cB;
        cstf(&zn[(g*4+rB)*512 + c2], zstage[rB*520 + c2] + 0.5f*(sum + b2v));
      }
      lbar(flags, w, epoch);
    }
    // ---- L1: liquid gate/tau pre-activations (final z in buffer 0) ----
    #pragma unroll
    for (int k=0;k<8;k++){
      int idx = k*256 + tid; int r = idx>>9, c = idx&511;
      const float* src = (kh==0) ? &Z[g*2048 + idx] : &H[g*2048 + idx];
      zstage[r*520 + c] = cldf(src);
    }
    __syncthreads();
    {
      int sub = tid>>7, l = tid&127;
      int r = l>>5, b = g*4+r;
      int c2 = (w&15)*32 + (l&31);
      const float* inrow = zstage + r*520;
      const float* Wc = (sub ? (kh==0 ? wsF+OF_LWTIT : wsF+OF_LWTHT)
                             : (kh==0 ? wsF+OF_LWIT  : wsF+OF_LWHT)) + (size_t)c2*512;
      float a0=0,a1=0,a2=0,a3=0;
      #pragma unroll 8
      for (int k=0;k<512;k+=4){
        float4 iv = *(const float4*)(inrow + k);
        float4 wv = *(const float4*)(Wc + k);
        a0 += iv.x*wv.x; a1 += iv.y*wv.y; a2 += iv.z*wv.z; a3 += iv.w*wv.w;
      }
      atomicAdd(sub ? &TA[b*512+c2] : &G[b*512+c2], (a0+a1)+(a2+a3));
    }
    lbar(flags, w, epoch);
  }
  // ---- epilogue: h-update for s=31 + snapshots (kernel boundary orders ZS/HS for k3) ----
  if (w < 16 && tid >= 128) {
    int idx = w*128 + (tid-128);
    int r = idx>>9, c2 = idx&511, b = g*4+r;
    float gv = tanhf(cldf(&G[b*512+c2]));
    float tv = softplusf_(cldf(&TA[b*512+c2])) + 1.0f;
    float hv = cldf(&H[b*512+c2]);
    float hn = hv + (gv - hv)/tv;
    if (write_pos[b] == 31) {
      cstf(&ZS[b*512+c2], cldf(&Z[b*512+c2]));   // buf0 = final z(31)
      cstf(&HS[b*512+c2], hn);
    }
  }
}

// ---------------- kernel 3: v_pred + decay-weighted scatter into M (v16 verbatim) ----------------
__global__ void __launch_bounds__(256) emma_k3(const float* z2v_W, const float* z2v_b,
                                               int* wsI, float* wsF)
{
  const int b = blockIdx.x, c = threadIdx.x;
  const float* zs = wsF + OF_ZS + b*512;
  const float* hs = wsF + OF_HS + b*512;
  float acc = z2v_b[c];
  for (int k=0;k<512;k++) acc += zs[k]*z2v_W[k*256 + c];
  for (int k=0;k<512;k++) acc += hs[k]*z2v_W[(512+k)*256 + c];
  __shared__ float red[256];
  red[c]=acc*acc; __syncthreads();
  for (int st=128; st; st>>=1){ if (c<st) red[c]+=red[c+st]; __syncthreads(); }
  float inv = 1.f/fmaxf(sqrtf(red[0]),1e-12f);
  float vp = acc*inv;
  float f = wsF[OF_DFAC + b];
  for (int j=0;j<16;j++){
    int slot = wsI[2048 + b*16 + j];
    float wj = wsF[OF_TOPW + b*16 + j];
    atomicAdd(&wsF[OF_M + (size_t)slot*256 + c], f*wj*vp);
  }
}

// ---------------- kernel 4: v_mem read, normalize, logits (v16 verbatim) ----------------
__global__ void __launch_bounds__(256) emma_k4(const float* value_W, int* wsI, float* wsF,
                                               float* out)
{
  const int b = blockIdx.x, c = threadIdx.x;
  float m = 0.f;
  for (int j=0;j<16;j++){
    int slot = wsI[2048 + b*16 + j];
    m += wsF[OF_TOPW + b*16 + j] * wsF[OF_M + (size_t)slot*256 + c];
  }
  __shared__ float red[256];
  __shared__ float vn[256];
  red[c]=m*m; __syncthreads();
  for (int st=128; st; st>>=1){ if (c<st) red[c]+=red[c+st]; __syncthreads(); }
  float inv = 1.f/fmaxf(sqrtf(red[0]),1e-12f);
  vn[c] = m*inv;
  __syncthreads();
  float scale = wsF[OF_SCALE];
  for (int q=0;q<4;q++){
    int val = q*256 + c;
    const float* row = value_W + (size_t)val*256;
    float d0=0,d1=0,d2=0,d3=0;
    #pragma unroll 4
    for (int k=0;k<256;k+=4){
      float4 rv = *(const float4*)(row + k);
      d0 += vn[k+0]*rv.x; d1 += vn[k+1]*rv.y; d2 += vn[k+2]*rv.z; d3 += vn[k+3]*rv.w;
    }
    out[b*1024 + val] = scale * wsF[OF_RNV + val] * ((d0+d1)+(d2+d3));
  }
}

extern "C" void kernel_launch(void* const* d_in, const int* in_sizes, int n_in,
                              void* d_out, int out_size, void* d_ws, size_t ws_size,
                              hipStream_t stream)
{
  const int*   tokens    = (const int*)  d_in[0];
  const int*   key_ids   = (const int*)  d_in[1];
  const int*   write_pos = (const int*)  d_in[2];
  const float* embed_W   = (const float*)d_in[5];
  const float* key_W     = (const float*)d_in[6];
  const float* value_W   = (const float*)d_in[7];
  const float* u_W1      = (const float*)d_in[8];
  const float* u_b1      = (const float*)d_in[9];
  const float* u_W2      = (const float*)d_in[10];
  const float* u_b2      = (const float*)d_in[11];
  const float* l_Wi      = (const float*)d_in[12];
  const float* l_Wh      = (const float*)d_in[13];
  const float* l_b       = (const float*)d_in[14];
  const float* l_Wti     = (const float*)d_in[15];
  const float* l_Wth     = (const float*)d_in[16];
  const float* l_bt      = (const float*)d_in[17];
  const float* h0        = (const float*)d_in[18];
  const float* z2v_W     = (const float*)d_in[19];
  const float* z2v_b     = (const float*)d_in[20];
  const float* lsr       = (const float*)d_in[21];
  const float* slot_keys = (const float*)d_in[22];

  int*   wsI = (int*)d_ws;
  float* wsF = (float*)((char*)d_ws + 16384);
  float* out = (float*)d_out;

  hipLaunchKernelGGL(emma_k1a, dim3(325), dim3(256), 0, stream,
                     key_ids, write_pos, key_W, value_W, slot_keys, lsr, wsI, wsF);
  hipLaunchKernelGGL(emma_k1b, dim3(32), dim3(256), 0, stream, wsI, wsF);
  // weight transposes (row-major [R][1<<shift] -> col-major):
  hipLaunchKernelGGL(emma_tr, dim3(512), dim3(256), 0, stream, u_W1,            wsF+OF_W1ZT, 10, 512*1024);
  hipLaunchKernelGGL(emma_tr, dim3(512), dim3(256), 0, stream, u_W1 + 512*1024, wsF+OF_W1XT, 10, 256*1024);
  hipLaunchKernelGGL(emma_tr, dim3(512), dim3(256), 0, stream, u_W2,            wsF+OF_W2T,   9, 1024*512);
  hipLaunchKernelGGL(emma_tr, dim3(512), dim3(256), 0, stream, l_Wi,            wsF+OF_LWIT,  9, 512*512);
  hipLaunchKernelGGL(emma_tr, dim3(512), dim3(256), 0, stream, l_Wh,            wsF+OF_LWHT,  9, 512*512);
  hipLaunchKernelGGL(emma_tr, dim3(512), dim3(256), 0, stream, l_Wti,           wsF+OF_LWTIT, 9, 512*512);
  hipLaunchKernelGGL(emma_tr, dim3(512), dim3(256), 0, stream, l_Wth,           wsF+OF_LWTHT, 9, 512*512);
  {
    void* args[] = { (void*)&tokens, (void*)&write_pos, (void*)&embed_W,
                     (void*)&u_b1, (void*)&u_b2, (void*)&l_b, (void*)&l_bt, (void*)&h0,
                     (void*)&wsI, (void*)&wsF };
    hipLaunchCooperativeKernel(reinterpret_cast<void*>(emma_k2), dim3(256), dim3(256),
                               args, 0, stream);
  }
  hipLaunchKernelGGL(emma_k3, dim3(32), dim3(256), 0, stream, z2v_W, z2v_b, wsI, wsF);
  hipLaunchKernelGGL(emma_k4, dim3(32), dim3(256), 0, stream, value_W, wsI, wsF, out);
}